// Round 6
// baseline (187.960 us; speedup 1.0000x reference)
//
#include <hip/hip_runtime.h>
#include <hip/hip_cooperative_groups.h>
namespace cg = cooperative_groups;

#define B 8
#define T 2048
#define D 256
#define L 8
#define E 64
#define BT (B*T)

typedef _Float16 f16;
typedef f16 f16x8 __attribute__((ext_vector_type(8)));
typedef float f32x4 __attribute__((ext_vector_type(4)));

// workspace layout (float offsets)
#define OFF_I   0
#define OFF_F   (OFF_I  + B*L*T)            // fp32
#define OFF_WT  (OFF_F  + B*L*T)            // f16 16*E*D
#define OFF_VT  (OFF_WT + 16*E*D/2)         // f16 B*L*E*T
#define OFF_KT  (OFF_VT + B*L*E*T/2)
#define OFF_CP  (OFF_KT + B*L*E*T/2)        // fp32 64*4*4160
#define OFF_X16 (OFF_CP + 64*4*4160)        // f16 BT*D
#define OFF_OQ  (OFF_X16 + BT*D/2)          // fp32 64*128

__global__ __launch_bounds__(512, 2) void k_mega(
        const float* __restrict__ x, const float* __restrict__ Wml,
        const float* __restrict__ bml, const float* __restrict__ Wlin,
        const float* __restrict__ blin, float* __restrict__ out,
        float* __restrict__ ibuf, float* __restrict__ fbuf,
        f16* __restrict__ Wt16, f16* __restrict__ Vt, f16* __restrict__ Kt,
        float* __restrict__ Cpart, f16* __restrict__ x16,
        float* __restrict__ oqbuf) {
    __shared__ __align__(16) char smem[49920];
    cg::grid_group grid = cg::this_grid();
    int tid = threadIdx.x;
    int bid = blockIdx.x;

    // ================= Phase 1: prep =================
    {
        float (*xs)[260] = (float(*)[260])smem;              // 32x260
        float (*wl)[260] = (float(*)[260])(smem + 33280);    // 16x260
        {
            int row = tid >> 5, c = (tid & 31) * 8;
            const float* src = Wlin + row * D + c;
            float4 v0 = *(const float4*)src, v1 = *(const float4*)(src + 4);
            *(float4*)&wl[row][c] = v0; *(float4*)&wl[row][c + 4] = v1;
        }
        #pragma unroll
        for (int u = 0; u < 2; ++u) {
            int t0 = bid * 64 + u * 32;
            int row = tid >> 4, q = (tid & 15) * 16;
            const float* src = x + (size_t)(t0 + row) * D + q;
            float4 a0 = *(const float4*)src;
            float4 a1 = *(const float4*)(src + 4);
            float4 a2 = *(const float4*)(src + 8);
            float4 a3 = *(const float4*)(src + 12);
            __syncthreads();
            *(float4*)&xs[row][q] = a0;
            *(float4*)&xs[row][q + 4] = a1;
            *(float4*)&xs[row][q + 8] = a2;
            *(float4*)&xs[row][q + 12] = a3;
            f16x8 h0, h1;
            h0[0]=(f16)a0.x; h0[1]=(f16)a0.y; h0[2]=(f16)a0.z; h0[3]=(f16)a0.w;
            h0[4]=(f16)a1.x; h0[5]=(f16)a1.y; h0[6]=(f16)a1.z; h0[7]=(f16)a1.w;
            h1[0]=(f16)a2.x; h1[1]=(f16)a2.y; h1[2]=(f16)a2.z; h1[3]=(f16)a2.w;
            h1[4]=(f16)a3.x; h1[5]=(f16)a3.y; h1[6]=(f16)a3.z; h1[7]=(f16)a3.w;
            *(f16x8*)(x16 + (size_t)(t0 + row) * D + q) = h0;
            *(f16x8*)(x16 + (size_t)(t0 + row) * D + q + 8) = h1;
            __syncthreads();
            int tt = tid >> 4, g = tid & 15;
            float acc = 0.f;
            for (int d = 0; d < D; d += 4) {
                float4 xv = *(const float4*)&xs[tt][d];
                float4 wv = *(const float4*)&wl[g][d];
                acc += xv.x * wv.x + xv.y * wv.y + xv.z * wv.z + xv.w * wv.w;
            }
            acc += blin[g];
            int t = t0 + tt; int b = t >> 11, trem = t & 2047;
            if (g < 8) ibuf[(b * L + g) * T + trem] = acc;
            else       fbuf[(b * L + (g - 8)) * T + trem] = acc;
        }
        if (bid < 64) {            // weight transpose unit (vkrow, dchunk)
            __syncthreads();
            float (*ts)[65] = (float(*)[65])smem;
            int vkrow = bid >> 2, dc = bid & 3;
            int wrow = 8 + vkrow, d0 = dc * 64;
            int r = tid >> 3, cq = (tid & 7) * 8;
            const float* src = Wml + ((size_t)wrow * D + d0 + r) * E + cq;
            float4 v0 = *(const float4*)src, v1 = *(const float4*)(src + 4);
            *(float4*)&ts[r][cq] = v0; *(float4*)&ts[r][cq + 4] = v1;
            __syncthreads();
            int e = tid >> 3, dq = (tid & 7) * 8;
            f16x8 o;
            #pragma unroll
            for (int j = 0; j < 8; ++j) o[j] = (f16)ts[dq + j][e];
            *(f16x8*)(Wt16 + ((size_t)vkrow * E + e) * D + d0 + dq) = o;
        } else if (bid < 72) {     // o/q projection at t = T-1, l = bid-64
            __syncthreads();
            float (*x8)[256] = (float(*)[256])smem;
            int l = bid - 64;
            {
                int bb = tid >> 6, c = (tid & 63) * 4;
                float4 v = *(const float4*)(x + ((size_t)(bb * T + (T - 1))) * D + c);
                *(float4*)&x8[bb][c] = v;
            }
            __syncthreads();
            #pragma unroll
            for (int r = 0; r < 2; ++r) {
                int idx = r * 512 + tid;
                int gate = idx >> 9, b = (idx >> 6) & 7, e = idx & 63;
                int row = gate ? (24 + l) : l;
                const float* gp = Wml + (size_t)row * D * E + e;
                float s = 0.f;
                for (int kk = 0; kk < D; ++kk) s += x8[b][kk] * gp[(size_t)kk * E];
                s += bml[row * E + e];
                oqbuf[(b * L + l) * 128 + gate * 64 + e] = s;
            }
        }
    }
    grid.sync();

    // ================= Phase 2: v,k projection MFMA =================
    {
        char* lds = smem;
        int bx = bid & 127, h = bid >> 7;
        int t0 = bx * 128;
        const f16* xa = x16 + (size_t)t0 * D;
        const f16* wb = Wt16 + (size_t)h * 8 * E * D;
        int wv = tid >> 6, lane = tid & 63;
        int wr = wv >> 2, wc = wv & 3;
        int q = lane >> 4, lr = lane & 15;
        int sa_t = tid >> 2, sa_q = tid & 3;
        f32x4 acc[4][8] = {};
        for (int ks = 0; ks < 8; ++ks) {
            int k0 = ks * 32;
            {
                f16x8 v = *(const f16x8*)(xa + (size_t)sa_t * D + k0 + sa_q * 8);
                int ba = sa_t * 64 + ((sa_q ^ ((sa_t >> 1) & 3)) << 4);
                *(f16x8*)(lds + ba) = v;
            }
            #pragma unroll
            for (int rr = 0; rr < 4; ++rr) {
                int r = rr * 128 + (tid >> 2);
                int c = tid & 3;
                f16x8 v = *(const f16x8*)(wb + (size_t)r * D + k0 + c * 8);
                int ba = 8192 + r * 64 + ((c ^ ((r >> 1) & 3)) << 4);
                *(f16x8*)(lds + ba) = v;
            }
            __syncthreads();
            f16x8 a[4], bf[8];
            #pragma unroll
            for (int m = 0; m < 4; ++m) {
                int t = wr * 64 + m * 16 + lr;
                int ba = t * 64 + ((q ^ ((t >> 1) & 3)) << 4);
                a[m] = *(const f16x8*)(lds + ba);
            }
            #pragma unroll
            for (int n = 0; n < 8; ++n) {
                int c = wc * 128 + n * 16 + lr;
                int ba = 8192 + c * 64 + ((q ^ ((c >> 1) & 3)) << 4);
                bf[n] = *(const f16x8*)(lds + ba);
            }
            #pragma unroll
            for (int m = 0; m < 4; ++m)
                #pragma unroll
                for (int n = 0; n < 8; ++n)
                    acc[m][n] = __builtin_amdgcn_mfma_f32_16x16x32_f16(
                        a[m], bf[n], acc[m][n], 0, 0, 0);
            __syncthreads();
        }
        const float* bp = bml + (size_t)(8 + h * 8) * E;
        int b_g = t0 >> 11, tin = t0 & 2047;
        f16* obase = h ? Kt : Vt;
        for (int p = 0; p < 4; ++p) {
            if (wc == p) {
                #pragma unroll
                for (int n = 0; n < 8; ++n) {
                    int cc = n * 16 + lr;
                    float bias = bp[p * 128 + cc];
                    int swz = (cc & 7) << 4;
                    #pragma unroll
                    for (int m = 0; m < 4; ++m) {
                        #pragma unroll
                        for (int r = 0; r < 4; r += 2) {
                            int t = wr * 64 + m * 16 + q * 4 + r;
                            union { f16 h2[2]; unsigned u; } pk;
                            pk.h2[0] = (f16)(acc[m][n][r] + bias);
                            pk.h2[1] = (f16)(acc[m][n][r + 1] + bias);
                            int ba = cc * 256 + ((t * 2) ^ swz);
                            *(unsigned*)(lds + ba) = pk.u;
                        }
                    }
                }
            }
            __syncthreads();
            {
                int cc = tid >> 2, part = tid & 3;
                int cg2 = p * 128 + cc;
                int l = cg2 >> 6, e = cg2 & 63;
                f16* dst = obase + ((size_t)((b_g * L + l) * E + e)) * T + tin + part * 32;
                int swz = (cc & 7) << 4;
                #pragma unroll
                for (int jj = 0; jj < 4; ++jj) {
                    int t = part * 32 + jj * 8;
                    int ba = cc * 256 + ((t * 2) ^ swz);
                    *(f16x8*)(dst + jj * 8) = *(const f16x8*)(lds + ba);
                }
            }
            __syncthreads();
        }
    }
    grid.sync();

    // ================= Phase 3: scan + weighted C-GEMM =================
    {
        int bl = bid >> 2, tc = bid & 3;
        float* red0  = (float*)smem;             // 16384 B
        float* red1  = (float*)(smem + 16384);   // 16384 B
        float* part  = (float*)(smem + 32768);   // 2048 B
        float* rmax  = (float*)(smem + 34816);   // 2048 B
        f16*   wlds  = (f16*)(smem + 36864);     // 1024 B
        float* redn0 = (float*)(smem + 37888);   // 256 B
        float* redn1 = (float*)(smem + 38144);   // 256 B
        // --- scan (full T, recomputed per block; deterministic) ---
        {
            const float* fp = fbuf + bl * T + tid * 4;
            const float* ip = ibuf + bl * T + tid * 4;
            float4 fa = *(const float4*)fp;
            float4 ia = *(const float4*)ip;
            float f0[4] = {fa.x, fa.y, fa.z, fa.w};
            float iv[4] = {ia.x, ia.y, ia.z, ia.w};
            float ls[4]; float run = 0.f;
            #pragma unroll
            for (int r = 0; r < 4; ++r) { run += f0[r]; ls[r] = run; }
            part[tid] = run;
            __syncthreads();
            float inc = run;
            #pragma unroll
            for (int s = 1; s < 512; s <<= 1) {
                float uu = (tid >= s) ? part[tid - s] : 0.f;
                __syncthreads();
                inc += uu;
                part[tid] = inc;
                __syncthreads();
            }
            float off = inc - run;
            float e[4]; float lmax = -1e30f;
            #pragma unroll
            for (int r = 0; r < 4; ++r) { e[r] = iv[r] - (off + ls[r]); lmax = fmaxf(lmax, e[r]); }
            rmax[tid] = lmax;
            __syncthreads();
            for (int s = 256; s > 0; s >>= 1) {
                if (tid < s) rmax[tid] = fmaxf(rmax[tid], rmax[tid + s]);
                __syncthreads();
            }
            float M = fmaxf(rmax[0], 0.0f);
            int tg = tid * 4;
            if ((tg >> 9) == tc) {
                union { f16 h[4]; unsigned long long u; } pw;
                #pragma unroll
                for (int r = 0; r < 4; ++r) pw.h[r] = (f16)__expf(e[r] - M);
                *(unsigned long long*)&wlds[tg & 511] = pw.u;
            }
            __syncthreads();
        }
        // --- weighted GEMM: 8 waves x 64-t each ---
        int wv = tid >> 6, lane = tid & 63;
        const f16* vp = Vt + (size_t)bl * E * T;
        const f16* kp = Kt + (size_t)bl * E * T;
        f32x4 acc[5][4] = {};
        int tw = tc * 512 + wv * 64;
        #pragma unroll
        for (int kc = 0; kc < 2; ++kc) {
            int lo = wv * 64 + kc * 32 + (lane >> 4) * 8;
            int tt = tc * 512 + lo;
            f16x8 wfrag = *(const f16x8*)&wlds[lo];
            f16x8 a[5], bf[4];
            #pragma unroll
            for (int m = 0; m < 4; ++m) {
                int i = m * 16 + (lane & 15);
                f16x8 v = *(const f16x8*)(vp + (size_t)i * T + tt);
                a[m] = v * wfrag;
            }
            a[4] = wfrag;
            #pragma unroll
            for (int nn = 0; nn < 4; ++nn) {
                int j = nn * 16 + (lane & 15);
                bf[nn] = *(const f16x8*)(kp + (size_t)j * T + tt);
            }
            #pragma unroll
            for (int m = 0; m < 5; ++m)
                #pragma unroll
                for (int nn = 0; nn < 4; ++nn)
                    acc[m][nn] = __builtin_amdgcn_mfma_f32_16x16x32_f16(
                        a[m], bf[nn], acc[m][nn], 0, 0, 0);
        }
        (void)tw;
        for (int rr = 0; rr < 4; ++rr) {
            if (wv == rr || wv == rr + 4) {
                float* rd = (wv < 4) ? red0 : red1;
                float* rn = (wv < 4) ? redn0 : redn1;
                #pragma unroll
                for (int m = 0; m < 4; ++m)
                    #pragma unroll
                    for (int nn = 0; nn < 4; ++nn)
                        #pragma unroll
                        for (int r = 0; r < 4; ++r) {
                            int row = m * 16 + (lane >> 4) * 4 + r;
                            int col = nn * 16 + (lane & 15);
                            if (rr == 0) rd[row * 64 + col] = acc[m][nn][r];
                            else         rd[row * 64 + col] += acc[m][nn][r];
                        }
                if ((lane >> 4) == 0) {
                    #pragma unroll
                    for (int nn = 0; nn < 4; ++nn) {
                        int col = nn * 16 + (lane & 15);
                        if (rr == 0) rn[col] = acc[4][nn][0];
                        else         rn[col] += acc[4][nn][0];
                    }
                }
            }
            __syncthreads();
        }
        float* cp = Cpart + ((size_t)bl * 4 + tc) * 4160;
        int idx = tid * 8;
        float4 s0, s1;
        {
            float4 a0 = *(const float4*)(red0 + idx);
            float4 b0 = *(const float4*)(red1 + idx);
            float4 a1 = *(const float4*)(red0 + idx + 4);
            float4 b1 = *(const float4*)(red1 + idx + 4);
            s0.x = a0.x + b0.x; s0.y = a0.y + b0.y; s0.z = a0.z + b0.z; s0.w = a0.w + b0.w;
            s1.x = a1.x + b1.x; s1.y = a1.y + b1.y; s1.z = a1.z + b1.z; s1.w = a1.w + b1.w;
        }
        *(float4*)(cp + idx) = s0;
        *(float4*)(cp + idx + 4) = s1;
        if (tid < 64) cp[4096 + tid] = redn0[tid] + redn1[tid];
    }
    grid.sync();

    // ================= Phase 4: final reduce + h =================
    if (bid < 64) {
        int bl = bid;
        float* Cs  = (float*)smem;               // 16384 B
        float* ns  = (float*)(smem + 16384);
        float* osb = (float*)(smem + 16640);
        float* qsb = (float*)(smem + 16896);
        const float* cp = Cpart + (size_t)bl * 4 * 4160;
        int idx = tid * 8;
        float4 s0 = {0,0,0,0}, s1 = {0,0,0,0};
        #pragma unroll
        for (int p = 0; p < 4; ++p) {
            float4 v0 = *(const float4*)(cp + p * 4160 + idx);
            float4 v1 = *(const float4*)(cp + p * 4160 + idx + 4);
            s0.x += v0.x; s0.y += v0.y; s0.z += v0.z; s0.w += v0.w;
            s1.x += v1.x; s1.y += v1.y; s1.z += v1.z; s1.w += v1.w;
        }
        *(float4*)&Cs[idx] = s0;
        *(float4*)&Cs[idx + 4] = s1;
        *(float4*)(out + 4096 + (size_t)bl * 4096 + idx) = s0;
        *(float4*)(out + 4096 + (size_t)bl * 4096 + idx + 4) = s1;
        if (tid < 64) {
            float s = 0.f;
            #pragma unroll
            for (int p = 0; p < 4; ++p) s += cp[p * 4160 + 4096 + tid];
            ns[tid] = s;
        }
        if (tid < 128) {
            float v = oqbuf[bl * 128 + tid];
            if (tid < 64) osb[tid] = v; else qsb[tid - 64] = v;
        }
        __syncthreads();
        if (tid < 64) {
            int j = tid;
            float hc = 0.f, nq = 0.f;
            for (int i2 = 0; i2 < E; ++i2) {
                hc += Cs[i2 * 64 + j] * qsb[i2];
                nq += ns[i2] * qsb[i2];
            }
            float denom = fmaxf(nq, 1.0f);
            float sg = 1.0f / (1.0f + __expf(-osb[j]));
            out[bl * 64 + j] = sg * hc / denom;
        }
    }
}

extern "C" void kernel_launch(void* const* d_in, const int* in_sizes, int n_in,
                              void* d_out, int out_size, void* d_ws, size_t ws_size,
                              hipStream_t stream) {
    const float* x    = (const float*)d_in[0];
    const float* Wml  = (const float*)d_in[1];
    const float* bml  = (const float*)d_in[2];
    const float* Wlin = (const float*)d_in[3];
    const float* blin = (const float*)d_in[4];
    float* out = (float*)d_out;
    float* ws = (float*)d_ws;
    float* ibuf  = ws + OFF_I;
    float* fbuf  = ws + OFF_F;
    f16*   Wt16  = (f16*)(ws + OFF_WT);
    f16*   Vt    = (f16*)(ws + OFF_VT);
    f16*   Kt    = (f16*)(ws + OFF_KT);
    float* Cpart = ws + OFF_CP;
    f16*   x16   = (f16*)(ws + OFF_X16);
    float* oqbuf = ws + OFF_OQ;

    void* args[] = {
        (void*)&x, (void*)&Wml, (void*)&bml, (void*)&Wlin, (void*)&blin,
        (void*)&out, (void*)&ibuf, (void*)&fbuf, (void*)&Wt16,
        (void*)&Vt, (void*)&Kt, (void*)&Cpart, (void*)&x16, (void*)&oqbuf
    };
    hipLaunchCooperativeKernel((void*)k_mega, dim3(256), dim3(512),
                               args, 0, stream);
}

// Round 7
// 76.876 us; speedup vs baseline: 2.4450x; 2.4450x over previous
//
#include <hip/hip_runtime.h>

#define B 8
#define T 2048
#define D 256
#define L 8
#define E 64
#define BT (B*T)

typedef _Float16 f16;
typedef f16 f16x8 __attribute__((ext_vector_type(8)));
typedef float f32x4 __attribute__((ext_vector_type(4)));

// workspace layout (float offsets)
#define OFF_I   0
#define OFF_F   (OFF_I  + B*L*T)            // fp32
#define OFF_WT  (OFF_F  + B*L*T)            // f16 16*E*D
#define OFF_VT  (OFF_WT + 16*E*D/2)         // f16 B*L*E*T
#define OFF_KT  (OFF_VT + B*L*E*T/2)
#define OFF_X16 (OFF_KT + B*L*E*T/2)        // f16 BT*D
#define OFF_OQ  (OFF_X16 + BT*D/2)          // fp32 64*128

// ---------------------------------------------------------------------------
// K1: prep.  bx<512: ifproj + x->f16 (one x pass);
//            512..527: v/k weight transpose; 528..535: o/q proj at t=T-1.
// ---------------------------------------------------------------------------
__global__ __launch_bounds__(256) void k_prep(const float* __restrict__ x,
        const float* __restrict__ Wlin, const float* __restrict__ blin,
        const float* __restrict__ Wml, const float* __restrict__ bml,
        float* __restrict__ ibuf, float* __restrict__ fbuf,
        f16* __restrict__ Wt16, f16* __restrict__ x16,
        float* __restrict__ oqbuf) {
    __shared__ __align__(16) char smem[49920];
    int tid = threadIdx.x;
    int bx = blockIdx.x;
    if (bx < 512) {
        float (*xs)[260] = (float(*)[260])smem;            // 32 x 260
        float (*wsm)[260] = (float(*)[260])(smem + 33280); // 16 x 260
        int t0 = bx * 32;
        {
            int row = tid >> 3, q = (tid & 7) * 32;
            const float* src = x + (size_t)(t0 + row) * D + q;
            f16* xdst = x16 + (size_t)(t0 + row) * D + q;
            #pragma unroll
            for (int j = 0; j < 4; ++j) {
                float4 v0 = *(const float4*)(src + j * 8);
                float4 v1 = *(const float4*)(src + j * 8 + 4);
                *(float4*)&xs[row][q + j * 8] = v0;
                *(float4*)&xs[row][q + j * 8 + 4] = v1;
                f16x8 h;
                h[0]=(f16)v0.x; h[1]=(f16)v0.y; h[2]=(f16)v0.z; h[3]=(f16)v0.w;
                h[4]=(f16)v1.x; h[5]=(f16)v1.y; h[6]=(f16)v1.z; h[7]=(f16)v1.w;
                *(f16x8*)(xdst + j * 8) = h;
            }
        }
        {
            int row = tid >> 4, c0 = (tid & 15) * 16;
            const float* src = Wlin + row * D + c0;
            #pragma unroll
            for (int j = 0; j < 4; ++j) {
                float4 v = *(const float4*)(src + j * 4);
                *(float4*)&wsm[row][c0 + j * 4] = v;
            }
        }
        __syncthreads();
        int tl = tid >> 4, g = tid & 15;
        float acc0 = 0.f, acc1 = 0.f;
        for (int i = 0; i < D; ++i) {
            float wv = wsm[g][i];
            acc0 += xs[tl * 2 + 0][i] * wv;
            acc1 += xs[tl * 2 + 1][i] * wv;
        }
        float bias = blin[g];
        float acc[2] = {acc0 + bias, acc1 + bias};
        #pragma unroll
        for (int u = 0; u < 2; ++u) {
            int t = t0 + tl * 2 + u;
            int b = t >> 11, tt = t & 2047;
            if (g < 8) ibuf[(b * L + g) * T + tt] = acc[u];
            else       fbuf[(b * L + (g - 8)) * T + tt] = acc[u];
        }
    } else if (bx < 528) {
        float (*ts)[65] = (float(*)[65])smem;              // 64 x 65
        int vkrow = bx - 512;
        int wrow = 8 + vkrow;
        for (int dc = 0; dc < 4; ++dc) {
            int d0 = dc * 64;
            int r = tid >> 2, cq = (tid & 3) * 16;
            const float* src = Wml + ((size_t)wrow * D + d0 + r) * E + cq;
            #pragma unroll
            for (int j = 0; j < 16; j += 4) {
                float4 v = *(const float4*)(src + j);
                ts[r][cq + j] = v.x; ts[r][cq + j + 1] = v.y;
                ts[r][cq + j + 2] = v.z; ts[r][cq + j + 3] = v.w;
            }
            __syncthreads();
            int e = tid >> 2, dq = (tid & 3) * 16;
            f16* dst = Wt16 + ((size_t)vkrow * E + e) * D + d0 + dq;
            f16x8 o0, o1;
            #pragma unroll
            for (int j = 0; j < 8; ++j) {
                o0[j] = (f16)ts[dq + j][e];
                o1[j] = (f16)ts[dq + 8 + j][e];
            }
            *(f16x8*)dst = o0;
            *(f16x8*)(dst + 8) = o1;
            __syncthreads();
        }
    } else {
        // o/q projection at t=T-1 for l = bx-528, all b, both gates
        float (*x8)[256] = (float(*)[256])smem;
        int l = bx - 528;
        {
            int bb = tid >> 5, c = (tid & 31) * 8;
            const float* src = x + ((size_t)(bb * T + (T - 1))) * D + c;
            float4 v0 = *(const float4*)src, v1 = *(const float4*)(src + 4);
            *(float4*)&x8[bb][c] = v0;
            *(float4*)&x8[bb][c + 4] = v1;
        }
        __syncthreads();
        #pragma unroll
        for (int r = 0; r < 4; ++r) {
            int idx = r * 256 + tid;
            int gate = idx >> 9, b = (idx >> 6) & 7, e = idx & 63;
            int row = gate ? (24 + l) : l;
            const float* gp = Wml + (size_t)row * D * E + e;
            float s = 0.f;
            for (int kk = 0; kk < D; ++kk) s += x8[b][kk] * gp[(size_t)kk * E];
            s += bml[row * E + e];
            oqbuf[(b * L + l) * 128 + gate * 64 + e] = s;
        }
    }
}

// ---------------------------------------------------------------------------
// K2: v,k projection via f16 MFMA.  Tile 128(M) x 512(N), BK=32, 512 thr.
// grid (BT/128, 2); by = h (0 -> v cols, 1 -> k cols).  Output (e,t).
// ---------------------------------------------------------------------------
__global__ __launch_bounds__(512) void k_vkproj3(const f16* __restrict__ x16,
        const f16* __restrict__ Wt16, const float* __restrict__ bml,
        f16* __restrict__ Vt, f16* __restrict__ Kt) {
    __shared__ __align__(16) char lds[40960];   // As 8KB | Bs 32KB
    int tid = threadIdx.x;
    int bx = blockIdx.x, h = blockIdx.y;
    int t0 = bx * 128;
    const f16* xa = x16 + (size_t)t0 * D;
    const f16* wb = Wt16 + (size_t)h * 8 * E * D;
    int wv = tid >> 6, lane = tid & 63;
    int wr = wv >> 2, wc = wv & 3;
    int q = lane >> 4, lr = lane & 15;
    int sa_t = tid >> 2, sa_q = tid & 3;
    f32x4 acc[4][8] = {};
    for (int ks = 0; ks < 8; ++ks) {
        int k0 = ks * 32;
        {
            f16x8 v = *(const f16x8*)(xa + (size_t)sa_t * D + k0 + sa_q * 8);
            int ba = sa_t * 64 + ((sa_q ^ ((sa_t >> 1) & 3)) << 4);
            *(f16x8*)(lds + ba) = v;
        }
        #pragma unroll
        for (int rr = 0; rr < 4; ++rr) {
            int r = rr * 128 + (tid >> 2);
            int c = tid & 3;
            f16x8 v = *(const f16x8*)(wb + (size_t)r * D + k0 + c * 8);
            int ba = 8192 + r * 64 + ((c ^ ((r >> 1) & 3)) << 4);
            *(f16x8*)(lds + ba) = v;
        }
        __syncthreads();
        f16x8 a[4], bf[8];
        #pragma unroll
        for (int m = 0; m < 4; ++m) {
            int t = wr * 64 + m * 16 + lr;
            int ba = t * 64 + ((q ^ ((t >> 1) & 3)) << 4);
            a[m] = *(const f16x8*)(lds + ba);
        }
        #pragma unroll
        for (int n = 0; n < 8; ++n) {
            int c = wc * 128 + n * 16 + lr;
            int ba = 8192 + c * 64 + ((q ^ ((c >> 1) & 3)) << 4);
            bf[n] = *(const f16x8*)(lds + ba);
        }
        #pragma unroll
        for (int m = 0; m < 4; ++m)
            #pragma unroll
            for (int n = 0; n < 8; ++n)
                acc[m][n] = __builtin_amdgcn_mfma_f32_16x16x32_f16(
                    a[m], bf[n], acc[m][n], 0, 0, 0);
        __syncthreads();
    }
    const float* bp = bml + (size_t)(8 + h * 8) * E;
    int b_g = t0 >> 11, tin = t0 & 2047;
    f16* obase = h ? Kt : Vt;
    for (int p = 0; p < 4; ++p) {
        if (wc == p) {
            #pragma unroll
            for (int n = 0; n < 8; ++n) {
                int cc = n * 16 + lr;
                float bias = bp[p * 128 + cc];
                int swz = (cc & 7) << 4;
                #pragma unroll
                for (int m = 0; m < 4; ++m) {
                    #pragma unroll
                    for (int r = 0; r < 4; r += 2) {
                        int t = wr * 64 + m * 16 + q * 4 + r;
                        union { f16 h2[2]; unsigned u; } pk;
                        pk.h2[0] = (f16)(acc[m][n][r] + bias);
                        pk.h2[1] = (f16)(acc[m][n][r + 1] + bias);
                        int ba = cc * 256 + ((t * 2) ^ swz);
                        *(unsigned*)(lds + ba) = pk.u;
                    }
                }
            }
        }
        __syncthreads();
        {
            int cc = tid >> 2, part = tid & 3;
            int cg2 = p * 128 + cc;
            int l = cg2 >> 6, e = cg2 & 63;
            f16* dst = obase + ((size_t)((b_g * L + l) * E + e)) * T + tin + part * 32;
            int swz = (cc & 7) << 4;
            #pragma unroll
            for (int jj = 0; jj < 4; ++jj) {
                int t = part * 32 + jj * 8;
                int ba = cc * 256 + ((t * 2) ^ swz);
                *(f16x8*)(dst + jj * 8) = *(const f16x8*)(lds + ba);
            }
        }
        __syncthreads();
    }
}

// ---------------------------------------------------------------------------
// K3: per-(b,l): inline scan + weighted C-GEMM over all T + reduce + h.
// grid 64 x 512 threads (8 waves x 256 t each).  Writes C and h to out.
// ---------------------------------------------------------------------------
__global__ __launch_bounds__(512) void k_cgemm_final(const f16* __restrict__ Vt,
        const f16* __restrict__ Kt, const float* __restrict__ ibuf,
        const float* __restrict__ fbuf, const float* __restrict__ oqbuf,
        float* __restrict__ out) {
    __shared__ __align__(16) char smem[41984];
    float* red0  = (float*)smem;             // 16384 B
    float* red1  = (float*)(smem + 16384);   // 16384 B
    float* part  = (float*)(smem + 32768);   // 2048 B
    float* rmax  = (float*)(smem + 34816);   // 2048 B
    f16*   wlds  = (f16*)(smem + 36864);     // 4096 B (full T)
    float* redn0 = (float*)(smem + 40960);   // 256 B
    float* redn1 = (float*)(smem + 41216);   // 256 B
    int tid = threadIdx.x;
    int bl = blockIdx.x;
    int wv = tid >> 6, lane = tid & 63;
    // ---- scan over full T ----
    {
        const float* fp = fbuf + bl * T + tid * 4;
        const float* ip = ibuf + bl * T + tid * 4;
        float4 fa = *(const float4*)fp;
        float4 ia = *(const float4*)ip;
        float f0[4] = {fa.x, fa.y, fa.z, fa.w};
        float iv[4] = {ia.x, ia.y, ia.z, ia.w};
        float ls[4]; float run = 0.f;
        #pragma unroll
        for (int r = 0; r < 4; ++r) { run += f0[r]; ls[r] = run; }
        part[tid] = run;
        __syncthreads();
        float inc = run;
        #pragma unroll
        for (int s = 1; s < 512; s <<= 1) {
            float uu = (tid >= s) ? part[tid - s] : 0.f;
            __syncthreads();
            inc += uu;
            part[tid] = inc;
            __syncthreads();
        }
        float off = inc - run;
        float e[4]; float lmax = -1e30f;
        #pragma unroll
        for (int r = 0; r < 4; ++r) { e[r] = iv[r] - (off + ls[r]); lmax = fmaxf(lmax, e[r]); }
        rmax[tid] = lmax;
        __syncthreads();
        for (int s = 256; s > 0; s >>= 1) {
            if (tid < s) rmax[tid] = fmaxf(rmax[tid], rmax[tid + s]);
            __syncthreads();
        }
        float M = fmaxf(rmax[0], 0.0f);
        union { f16 h[4]; unsigned long long u; } pw;
        #pragma unroll
        for (int r = 0; r < 4; ++r) pw.h[r] = (f16)__expf(e[r] - M);
        *(unsigned long long*)&wlds[tid * 4] = pw.u;
        __syncthreads();
    }
    // ---- weighted GEMM: wave wv covers t in [wv*256, wv*256+256) ----
    const f16* vp = Vt + (size_t)bl * E * T;
    const f16* kp = Kt + (size_t)bl * E * T;
    f32x4 acc[5][4] = {};
    #pragma unroll
    for (int kc = 0; kc < 8; ++kc) {
        int tt = wv * 256 + kc * 32 + (lane >> 4) * 8;
        f16x8 wfrag = *(const f16x8*)&wlds[tt];
        f16x8 a[5], bf[4];
        #pragma unroll
        for (int m = 0; m < 4; ++m) {
            int i = m * 16 + (lane & 15);
            f16x8 v = *(const f16x8*)(vp + (size_t)i * T + tt);
            a[m] = v * wfrag;
        }
        a[4] = wfrag;
        #pragma unroll
        for (int nn = 0; nn < 4; ++nn) {
            int j = nn * 16 + (lane & 15);
            bf[nn] = *(const f16x8*)(kp + (size_t)j * T + tt);
        }
        #pragma unroll
        for (int m = 0; m < 5; ++m)
            #pragma unroll
            for (int nn = 0; nn < 4; ++nn)
                acc[m][nn] = __builtin_amdgcn_mfma_f32_16x16x32_f16(
                    a[m], bf[nn], acc[m][nn], 0, 0, 0);
    }
    // ---- 8-wave reduction: pairs (rr, rr+4) -> red0/red1 ----
    for (int rr = 0; rr < 4; ++rr) {
        if (wv == rr || wv == rr + 4) {
            float* rd = (wv < 4) ? red0 : red1;
            float* rn = (wv < 4) ? redn0 : redn1;
            #pragma unroll
            for (int m = 0; m < 4; ++m)
                #pragma unroll
                for (int nn = 0; nn < 4; ++nn)
                    #pragma unroll
                    for (int r = 0; r < 4; ++r) {
                        int row = m * 16 + (lane >> 4) * 4 + r;
                        int col = nn * 16 + (lane & 15);
                        if (rr == 0) rd[row * 64 + col] = acc[m][nn][r];
                        else         rd[row * 64 + col] += acc[m][nn][r];
                    }
            if ((lane >> 4) == 0) {
                #pragma unroll
                for (int nn = 0; nn < 4; ++nn) {
                    int col = nn * 16 + (lane & 15);
                    if (rr == 0) rn[col] = acc[4][nn][0];
                    else         rn[col] += acc[4][nn][0];
                }
            }
        }
        __syncthreads();
    }
    // ---- combine halves, write C to out, keep in red0 for h ----
    {
        int idx = tid * 8;
        float4 a0 = *(const float4*)(red0 + idx);
        float4 b0 = *(const float4*)(red1 + idx);
        float4 a1 = *(const float4*)(red0 + idx + 4);
        float4 b1 = *(const float4*)(red1 + idx + 4);
        float4 s0 = {a0.x + b0.x, a0.y + b0.y, a0.z + b0.z, a0.w + b0.w};
        float4 s1 = {a1.x + b1.x, a1.y + b1.y, a1.z + b1.z, a1.w + b1.w};
        *(float4*)(out + 4096 + (size_t)bl * 4096 + idx) = s0;
        *(float4*)(out + 4096 + (size_t)bl * 4096 + idx + 4) = s1;
        *(float4*)(red0 + idx) = s0;
        *(float4*)(red0 + idx + 4) = s1;
        if (tid < 64) redn0[tid] = redn0[tid] + redn1[tid];
    }
    __syncthreads();
    if (tid < 64) {
        int j = tid;
        float hc = 0.f, nq = 0.f;
        const float* oq = oqbuf + bl * 128;
        for (int i2 = 0; i2 < E; ++i2) {
            float qv = oq[64 + i2];
            hc += red0[i2 * 64 + j] * qv;
            nq += redn0[i2] * qv;
        }
        float denom = fmaxf(nq, 1.0f);
        float sg = 1.0f / (1.0f + __expf(-oq[j]));
        out[bl * 64 + j] = sg * hc / denom;
    }
}

extern "C" void kernel_launch(void* const* d_in, const int* in_sizes, int n_in,
                              void* d_out, int out_size, void* d_ws, size_t ws_size,
                              hipStream_t stream) {
    const float* x    = (const float*)d_in[0];
    const float* Wml  = (const float*)d_in[1];
    const float* bml  = (const float*)d_in[2];
    const float* Wlin = (const float*)d_in[3];
    const float* blin = (const float*)d_in[4];
    float* out = (float*)d_out;
    float* ws = (float*)d_ws;
    float* ibuf  = ws + OFF_I;
    float* fbuf  = ws + OFF_F;
    f16*   Wt16  = (f16*)(ws + OFF_WT);
    f16*   Vt    = (f16*)(ws + OFF_VT);
    f16*   Kt    = (f16*)(ws + OFF_KT);
    f16*   x16   = (f16*)(ws + OFF_X16);
    float* oqbuf = ws + OFF_OQ;

    k_prep<<<536, 256, 0, stream>>>(x, Wlin, blin, Wml, bml,
                                    ibuf, fbuf, Wt16, x16, oqbuf);
    k_vkproj3<<<dim3(BT / 128, 2), 512, 0, stream>>>(x16, Wt16, bml, Vt, Kt);
    k_cgemm_final<<<B * L, 512, 0, stream>>>(Vt, Kt, ibuf, fbuf, oqbuf, out);
}